// Round 1
// baseline (1865.583 us; speedup 1.0000x reference)
//
#include <hip/hip_runtime.h>
#include <hip/hip_fp16.h>

#define NN 16
#define BB 16
#define TT 512
#define II 256
#define HH 512

typedef _Float16 half2_t __attribute__((ext_vector_type(2)));
typedef _Float16 f16x8  __attribute__((ext_vector_type(8)));
typedef float    f32x4  __attribute__((ext_vector_type(4)));

#if defined(__has_builtin)
#  if __has_builtin(__builtin_amdgcn_fdot2)
#    define USE_FDOT2 1
#  endif
#endif

__device__ __forceinline__ float fdot2(half2_t a, half2_t b, float c) {
#ifdef USE_FDOT2
    return __builtin_amdgcn_fdot2(a, b, c, false);
#else
    return c + (float)a[0] * (float)b[0] + (float)a[1] * (float)b[1];
#endif
}

__device__ __forceinline__ half2_t bch(unsigned u) {
    return __builtin_bit_cast(half2_t, u);
}
__device__ __forceinline__ unsigned hcb(half2_t h) {
    return __builtin_bit_cast(unsigned, h);
}

// ---------------------------------------------------------------------------
// Kernel 1: pre[n][bt][h] = sum_i x[n][bt][i]*w_ih[n][h][i] + b_ih[n][h] + b_hh[n][h]
// MFMA version: 128(bt) x 128(h) tile, K=256 in two BK=128 passes.
// 4 waves, each owns a 64x64 quadrant = 4x4 frags of mfma_f32_16x16x32_f16.
// fp32 global -> cvt fp16 -> LDS (reg-staged; +8-half row pad kills the
// stride-272B bank conflict: frag reads spread perfectly over 32 banks).
// ---------------------------------------------------------------------------
#define K1_LDA 136                                   // 128 + 8 halves
#define K1_LDS_BYTES (2 * 128 * K1_LDA * 2)          // A + B = 69632 B -> 2 WG/CU

__global__ __launch_bounds__(256, 2) void k1_xproj(
    const float* __restrict__ x,
    const float* __restrict__ w_ih,
    const float* __restrict__ b_ih,
    const float* __restrict__ b_hh,
    float* __restrict__ pre)
{
    extern __shared__ char smem[];
    _Float16* A2 = (_Float16*)smem;                  // [128][136]
    _Float16* B2 = (_Float16*)smem + 128 * K1_LDA;   // [128][136]

    const int tid = threadIdx.x;
    const int n   = blockIdx.z;
    const int h0  = blockIdx.x * 128;                // h-tile (4)
    const int bt0 = blockIdx.y * 128;                // bt-tile (64)

    const float* xa = x    + ((size_t)n * (BB * TT) + bt0) * II;
    const float* wb = w_ih + ((size_t)n * HH + h0) * II;

    const int lane = tid & 63;
    const int wid  = tid >> 6;
    const int wr   = (wid >> 1) * 64;   // wave's bt offset in tile
    const int wc   = (wid & 1) * 64;    // wave's h  offset in tile
    const int l15  = lane & 15;
    const int kb   = (lane >> 4) * 8;   // k sub-offset within frag

    f32x4 acc[4][4];
    #pragma unroll
    for (int m = 0; m < 4; ++m)
        #pragma unroll
        for (int c = 0; c < 4; ++c)
            acc[m][c] = (f32x4){0.f, 0.f, 0.f, 0.f};

    for (int kc = 0; kc < 2; ++kc) {
        // stage: 128 rows x 32 float4 each for A and B (2 rows/wave/rep, coalesced)
        #pragma unroll
        for (int rep = 0; rep < 16; ++rep) {
            int flat = rep * 256 + tid;
            int row  = flat >> 5;
            int c4   = flat & 31;
            float4 v = reinterpret_cast<const float4*>(xa + (size_t)row * II + kc * 128)[c4];
            uint2 ua;
            ua.x = hcb(half2_t{(_Float16)v.x, (_Float16)v.y});
            ua.y = hcb(half2_t{(_Float16)v.z, (_Float16)v.w});
            *reinterpret_cast<uint2*>(&A2[row * K1_LDA + c4 * 4]) = ua;

            float4 w = reinterpret_cast<const float4*>(wb + (size_t)row * II + kc * 128)[c4];
            uint2 uw;
            uw.x = hcb(half2_t{(_Float16)w.x, (_Float16)w.y});
            uw.y = hcb(half2_t{(_Float16)w.z, (_Float16)w.w});
            *reinterpret_cast<uint2*>(&B2[row * K1_LDA + c4 * 4]) = uw;
        }
        __syncthreads();

        #pragma unroll
        for (int kk = 0; kk < 4; ++kk) {             // BK=128 -> 4 k-steps of 32
            f16x8 af[4], bf[4];
            #pragma unroll
            for (int m = 0; m < 4; ++m)
                af[m] = *reinterpret_cast<const f16x8*>(
                    &A2[(wr + m * 16 + l15) * K1_LDA + kk * 32 + kb]);
            #pragma unroll
            for (int c = 0; c < 4; ++c)
                bf[c] = *reinterpret_cast<const f16x8*>(
                    &B2[(wc + c * 16 + l15) * K1_LDA + kk * 32 + kb]);
            #pragma unroll
            for (int m = 0; m < 4; ++m)
                #pragma unroll
                for (int c = 0; c < 4; ++c)
                    acc[m][c] = __builtin_amdgcn_mfma_f32_16x16x32_f16(
                        af[m], bf[c], acc[m][c], 0, 0, 0);
        }
        __syncthreads();
    }

    // epilogue: C/D layout col=lane&15 (h), row=(lane>>4)*4+reg (bt)
    const int crow = (lane >> 4) * 4;
    float bias[4];
    #pragma unroll
    for (int c = 0; c < 4; ++c) {
        int h = h0 + wc + c * 16 + l15;
        bias[c] = b_ih[n * HH + h] + b_hh[n * HH + h];
    }
    float* prow = pre + ((size_t)n * (BB * TT) + bt0) * HH + h0;
    #pragma unroll
    for (int m = 0; m < 4; ++m)
        #pragma unroll
        for (int c = 0; c < 4; ++c)
            #pragma unroll
            for (int r = 0; r < 4; ++r)
                prow[(size_t)(wr + m * 16 + crow + r) * HH + wc + c * 16 + l15]
                    = acc[m][c][r] + bias[c];
}

// ---------------------------------------------------------------------------
// Kernel 2: persistent recurrence. One WG per (n,b), 1024 threads, 1 WG/CU.
// NEW vs prev round:
//   - pair mapping o=tid>>1, kh=tid&1: K-split partners are adjacent lanes,
//     reduce via __shfl_xor(s,1) -> no partial[] LDS round-trip
//   - tanh tail computed by ALL lanes (redundantly per pair) -> no 8-wave tail
//   - h double-buffered (2 x 1 KB): step t reads hb[p], writes hb[p^1];
//     ONE __syncthreads() per step (it separates t's reads from t+1's writes)
// Weight storage unchanged: 96 half2 in regs + 32 half2 in LDS per thread.
// ---------------------------------------------------------------------------
#define LREG 96
#define K2_LDS (2 * 1024 + 16 * 1024 * 8)   // 2 h-buffers + wlds = 133120 B

__global__ __launch_bounds__(1024, 4) void k2_rnn(
    const float* __restrict__ w_hh,
    float* __restrict__ out,     // [N][B][T][H]: pre on entry, h on exit
    float* __restrict__ hn)      // [N][B][H]
{
    extern __shared__ char smem[];
    _Float16* hb = (_Float16*)smem;                   // [2][512]
    uint2* wlds  = (uint2*)(smem + 2048);             // [16][1024]

    const int tid = threadIdx.x;
    const int o   = tid >> 1;          // output index, pair-shared
    const int kh  = tid & 1;           // K-half
    const int n   = blockIdx.x >> 4;
    const int b   = blockIdx.x & 15;

    const float* wrow = w_hh + ((size_t)(n * HH + o)) * HH + kh * 256;

    // Register-resident weights: halves [0,192)
    half2_t wr[LREG];
    #pragma unroll
    for (int j = 0; j < 48; ++j) {
        float4 v = reinterpret_cast<const float4*>(wrow)[j];
        wr[2 * j]     = half2_t{(_Float16)v.x, (_Float16)v.y};
        wr[2 * j + 1] = half2_t{(_Float16)v.z, (_Float16)v.w};
    }
    // LDS-resident weights: halves [192,256) -> 16 uint2 per thread
    #pragma unroll
    for (int j = 0; j < 16; ++j) {
        float4 v = reinterpret_cast<const float4*>(wrow + 192)[j];
        uint2 u;
        u.x = hcb(half2_t{(_Float16)v.x, (_Float16)v.y});
        u.y = hcb(half2_t{(_Float16)v.z, (_Float16)v.w});
        wlds[j * 1024 + tid] = u;
    }

    float* mybase = out + ((size_t)(n * BB + b)) * TT * HH + o;

    hb[tid] = (_Float16)0.f;                 // zero both buffers (1024 halves)
    float pre_next = mybase[0];              // pair-duplicate load, same addr
    __syncthreads();

    float hlast = 0.f;
    int p = 0;
    for (int t = 0; t < TT; ++t) {
        const uint4* hv = reinterpret_cast<const uint4*>(hb + p * 512 + kh * 256);
        float acc0 = 0.f, acc1 = 0.f;
        #pragma unroll
        for (int j = 0; j < 24; ++j) {              // register-weight part
            uint4 hq = hv[j];                       // 2-address broadcast read
            acc0 = fdot2(wr[4 * j + 0], bch(hq.x), acc0);
            acc1 = fdot2(wr[4 * j + 1], bch(hq.y), acc1);
            acc0 = fdot2(wr[4 * j + 2], bch(hq.z), acc0);
            acc1 = fdot2(wr[4 * j + 3], bch(hq.w), acc1);
        }
        #pragma unroll
        for (int j = 0; j < 8; ++j) {               // LDS-weight part
            uint4 hq = hv[24 + j];
            uint2 w0 = wlds[(2 * j) * 1024 + tid];
            uint2 w1 = wlds[(2 * j + 1) * 1024 + tid];
            acc0 = fdot2(bch(w0.x), bch(hq.x), acc0);
            acc1 = fdot2(bch(w0.y), bch(hq.y), acc1);
            acc0 = fdot2(bch(w1.x), bch(hq.z), acc0);
            acc1 = fdot2(bch(w1.y), bch(hq.w), acc1);
        }
        float s = acc0 + acc1;
        s += __shfl_xor(s, 1);                      // pair reduce, no LDS
        s += pre_next;
        s = fminf(fmaxf(s, -15.f), 15.f);
        float e = __expf(2.0f * s);
        float v = (e - 1.0f) / (e + 1.0f);          // tanh(s), all lanes
        if (kh == 0) {
            hb[(p ^ 1) * 512 + o] = (_Float16)v;    // h for step t+1
            mybase[(size_t)t * HH] = v;             // overwrite pre[t] with h[t]
        }
        hlast = v;
        if (t + 1 < TT) pre_next = mybase[(size_t)(t + 1) * HH];
        __syncthreads();                            // ONE barrier per step
        p ^= 1;
    }

    if (kh == 0) hn[((size_t)(n * BB + b)) * HH + o] = hlast;
}

// ---------------------------------------------------------------------------
extern "C" void kernel_launch(void* const* d_in, const int* in_sizes, int n_in,
                              void* d_out, int out_size, void* d_ws, size_t ws_size,
                              hipStream_t stream) {
    const float* x    = (const float*)d_in[0];
    const float* w_ih = (const float*)d_in[1];
    const float* w_hh = (const float*)d_in[2];
    const float* b_ih = (const float*)d_in[3];
    const float* b_hh = (const float*)d_in[4];

    float* out = (float*)d_out;                       // [N][B][T][H]
    float* hn  = out + (size_t)NN * BB * TT * HH;     // [N][B][H] tail

    hipFuncSetAttribute(reinterpret_cast<const void*>(k1_xproj),
                        hipFuncAttributeMaxDynamicSharedMemorySize, K1_LDS_BYTES);
    hipLaunchKernelGGL(k1_xproj, dim3(4, 64, 16), dim3(256), K1_LDS_BYTES, stream,
                       x, w_ih, b_ih, b_hh, out);

    hipFuncSetAttribute(reinterpret_cast<const void*>(k2_rnn),
                        hipFuncAttributeMaxDynamicSharedMemorySize, K2_LDS);
    hipLaunchKernelGGL(k2_rnn, dim3(NN * BB), dim3(1024), K2_LDS, stream,
                       w_hh, out, hn);
}

// Round 2
// 1746.729 us; speedup vs baseline: 1.0680x; 1.0680x over previous
//
#include <hip/hip_runtime.h>
#include <hip/hip_fp16.h>

#define NN 16
#define BB 16
#define TT 512
#define II 256
#define HH 512

typedef _Float16 half2_t __attribute__((ext_vector_type(2)));
typedef _Float16 f16x8  __attribute__((ext_vector_type(8)));
typedef float    f32x4  __attribute__((ext_vector_type(4)));

#if defined(__has_builtin)
#  if __has_builtin(__builtin_amdgcn_fdot2)
#    define USE_FDOT2 1
#  endif
#endif

__device__ __forceinline__ float fdot2(half2_t a, half2_t b, float c) {
#ifdef USE_FDOT2
    return __builtin_amdgcn_fdot2(a, b, c, false);
#else
    return c + (float)a[0] * (float)b[0] + (float)a[1] * (float)b[1];
#endif
}

__device__ __forceinline__ half2_t bch(unsigned u) {
    return __builtin_bit_cast(half2_t, u);
}
__device__ __forceinline__ unsigned hcb(half2_t h) {
    return __builtin_bit_cast(unsigned, h);
}

// ---------------------------------------------------------------------------
// Kernel 1: pre[n][bt][h] = sum_i x[n][bt][i]*w_ih[n][h][i] + b_ih[n][h] + b_hh[n][h]
// MFMA version: 128(bt) x 128(h) tile, K=256 in two BK=128 passes.
// 4 waves, each owns a 64x64 quadrant = 4x4 frags of mfma_f32_16x16x32_f16.
// UNCHANGED from previous round (isolating the k2 fix).
// ---------------------------------------------------------------------------
#define K1_LDA 136                                   // 128 + 8 halves
#define K1_LDS_BYTES (2 * 128 * K1_LDA * 2)          // A + B = 69632 B -> 2 WG/CU

__global__ __launch_bounds__(256, 2) void k1_xproj(
    const float* __restrict__ x,
    const float* __restrict__ w_ih,
    const float* __restrict__ b_ih,
    const float* __restrict__ b_hh,
    float* __restrict__ pre)
{
    extern __shared__ char smem[];
    _Float16* A2 = (_Float16*)smem;                  // [128][136]
    _Float16* B2 = (_Float16*)smem + 128 * K1_LDA;   // [128][136]

    const int tid = threadIdx.x;
    const int n   = blockIdx.z;
    const int h0  = blockIdx.x * 128;                // h-tile (4)
    const int bt0 = blockIdx.y * 128;                // bt-tile (64)

    const float* xa = x    + ((size_t)n * (BB * TT) + bt0) * II;
    const float* wb = w_ih + ((size_t)n * HH + h0) * II;

    const int lane = tid & 63;
    const int wid  = tid >> 6;
    const int wr   = (wid >> 1) * 64;   // wave's bt offset in tile
    const int wc   = (wid & 1) * 64;    // wave's h  offset in tile
    const int l15  = lane & 15;
    const int kb   = (lane >> 4) * 8;   // k sub-offset within frag

    f32x4 acc[4][4];
    #pragma unroll
    for (int m = 0; m < 4; ++m)
        #pragma unroll
        for (int c = 0; c < 4; ++c)
            acc[m][c] = (f32x4){0.f, 0.f, 0.f, 0.f};

    for (int kc = 0; kc < 2; ++kc) {
        // stage: 128 rows x 32 float4 each for A and B (2 rows/wave/rep, coalesced)
        #pragma unroll
        for (int rep = 0; rep < 16; ++rep) {
            int flat = rep * 256 + tid;
            int row  = flat >> 5;
            int c4   = flat & 31;
            float4 v = reinterpret_cast<const float4*>(xa + (size_t)row * II + kc * 128)[c4];
            uint2 ua;
            ua.x = hcb(half2_t{(_Float16)v.x, (_Float16)v.y});
            ua.y = hcb(half2_t{(_Float16)v.z, (_Float16)v.w});
            *reinterpret_cast<uint2*>(&A2[row * K1_LDA + c4 * 4]) = ua;

            float4 w = reinterpret_cast<const float4*>(wb + (size_t)row * II + kc * 128)[c4];
            uint2 uw;
            uw.x = hcb(half2_t{(_Float16)w.x, (_Float16)w.y});
            uw.y = hcb(half2_t{(_Float16)w.z, (_Float16)w.w});
            *reinterpret_cast<uint2*>(&B2[row * K1_LDA + c4 * 4]) = uw;
        }
        __syncthreads();

        #pragma unroll
        for (int kk = 0; kk < 4; ++kk) {             // BK=128 -> 4 k-steps of 32
            f16x8 af[4], bf[4];
            #pragma unroll
            for (int m = 0; m < 4; ++m)
                af[m] = *reinterpret_cast<const f16x8*>(
                    &A2[(wr + m * 16 + l15) * K1_LDA + kk * 32 + kb]);
            #pragma unroll
            for (int c = 0; c < 4; ++c)
                bf[c] = *reinterpret_cast<const f16x8*>(
                    &B2[(wc + c * 16 + l15) * K1_LDA + kk * 32 + kb]);
            #pragma unroll
            for (int m = 0; m < 4; ++m)
                #pragma unroll
                for (int c = 0; c < 4; ++c)
                    acc[m][c] = __builtin_amdgcn_mfma_f32_16x16x32_f16(
                        af[m], bf[c], acc[m][c], 0, 0, 0);
        }
        __syncthreads();
    }

    // epilogue: C/D layout col=lane&15 (h), row=(lane>>4)*4+reg (bt)
    const int crow = (lane >> 4) * 4;
    float bias[4];
    #pragma unroll
    for (int c = 0; c < 4; ++c) {
        int h = h0 + wc + c * 16 + l15;
        bias[c] = b_ih[n * HH + h] + b_hh[n * HH + h];
    }
    float* prow = pre + ((size_t)n * (BB * TT) + bt0) * HH + h0;
    #pragma unroll
    for (int m = 0; m < 4; ++m)
        #pragma unroll
        for (int c = 0; c < 4; ++c)
            #pragma unroll
            for (int r = 0; r < 4; ++r)
                prow[(size_t)(wr + m * 16 + crow + r) * HH + wc + c * 16 + l15]
                    = acc[m][c][r] + bias[c];
}

// ---------------------------------------------------------------------------
// Kernel 2: persistent recurrence. One WG per (n,b), 1024 threads, 1 WG/CU.
// vs round 1: h buffer regions PADDED apart (272-half stride = 544 B ≡ +8
// banks) so the two per-wave ds_read_b128 addresses (kh=0 even lanes /
// kh=1 odd lanes) hit DISJOINT bank quads -> 0 conflicts, each a 32-lane
// broadcast. Keeps: single barrier/step, shfl_xor pair-reduce, all-lane
// tanh. New: 4 accumulator chains (32-deep each instead of 64-deep x2).
// ---------------------------------------------------------------------------
#define LREG  96
#define HREG  272                            // padded per-kh region, halves
#define HBUF  (2 * HREG)                     // one h buffer (544 halves)
#define K2_LDS (2 * HBUF * 2 + 16 * 1024 * 8)   // 2176 + 131072 = 133248 B

__global__ __launch_bounds__(1024, 4) void k2_rnn(
    const float* __restrict__ w_hh,
    float* __restrict__ out,     // [N][B][T][H]: pre on entry, h on exit
    float* __restrict__ hn)      // [N][B][H]
{
    extern __shared__ char smem[];
    _Float16* hb = (_Float16*)smem;                   // [2][2][272] halves
    uint2* wlds  = (uint2*)(smem + 2 * HBUF * 2);     // [16][1024]

    const int tid = threadIdx.x;
    const int o   = tid >> 1;          // output index, pair-shared
    const int kh  = tid & 1;           // K-half
    const int n   = blockIdx.x >> 4;
    const int b   = blockIdx.x & 15;

    const float* wrow = w_hh + ((size_t)(n * HH + o)) * HH + kh * 256;

    // Register-resident weights: halves [0,192)
    half2_t wr[LREG];
    #pragma unroll
    for (int j = 0; j < 48; ++j) {
        float4 v = reinterpret_cast<const float4*>(wrow)[j];
        wr[2 * j]     = half2_t{(_Float16)v.x, (_Float16)v.y};
        wr[2 * j + 1] = half2_t{(_Float16)v.z, (_Float16)v.w};
    }
    // LDS-resident weights: halves [192,256) -> 16 uint2 per thread
    #pragma unroll
    for (int j = 0; j < 16; ++j) {
        float4 v = reinterpret_cast<const float4*>(wrow + 192)[j];
        uint2 u;
        u.x = hcb(half2_t{(_Float16)v.x, (_Float16)v.y});
        u.y = hcb(half2_t{(_Float16)v.z, (_Float16)v.w});
        wlds[j * 1024 + tid] = u;
    }

    float* mybase = out + ((size_t)(n * BB + b)) * TT * HH + o;

    // zero both h buffers (2*544 = 1088 halves, incl. pads)
    hb[tid] = (_Float16)0.f;
    if (tid < 2 * HBUF - 1024) hb[1024 + tid] = (_Float16)0.f;
    float pre_next = mybase[0];              // pair-duplicate load, same addr
    __syncthreads();

    // write offset inside a buffer: h[o] lives in region (o>>8) at (o&255)
    const int wo = (o & 255) + (o >> 8) * HREG;

    float hlast = 0.f;
    int p = 0;
    for (int t = 0; t < TT; ++t) {
        const uint4* hv = reinterpret_cast<const uint4*>(hb + p * HBUF + kh * HREG);
        float a0 = 0.f, a1 = 0.f, a2 = 0.f, a3 = 0.f;
        #pragma unroll
        for (int j = 0; j < 24; ++j) {              // register-weight part
            uint4 hq = hv[j];                       // 2-addr bank-disjoint bcast
            a0 = fdot2(wr[4 * j + 0], bch(hq.x), a0);
            a1 = fdot2(wr[4 * j + 1], bch(hq.y), a1);
            a2 = fdot2(wr[4 * j + 2], bch(hq.z), a2);
            a3 = fdot2(wr[4 * j + 3], bch(hq.w), a3);
        }
        #pragma unroll
        for (int j = 0; j < 8; ++j) {               // LDS-weight part
            uint4 hq = hv[24 + j];
            uint2 w0 = wlds[(2 * j) * 1024 + tid];
            uint2 w1 = wlds[(2 * j + 1) * 1024 + tid];
            a0 = fdot2(bch(w0.x), bch(hq.x), a0);
            a1 = fdot2(bch(w0.y), bch(hq.y), a1);
            a2 = fdot2(bch(w1.x), bch(hq.z), a2);
            a3 = fdot2(bch(w1.y), bch(hq.w), a3);
        }
        float s = (a0 + a2) + (a1 + a3);
        s += __shfl_xor(s, 1);                      // pair reduce (DPP, no LDS)
        s += pre_next;
        s = fminf(fmaxf(s, -15.f), 15.f);
        float e = __expf(2.0f * s);
        float v = (e - 1.0f) / (e + 1.0f);          // tanh(s), all lanes
        if (kh == 0) {
            hb[(p ^ 1) * HBUF + wo] = (_Float16)v;  // h for step t+1
            mybase[(size_t)t * HH] = v;             // overwrite pre[t] with h[t]
        }
        hlast = v;
        if (t + 1 < TT) pre_next = mybase[(size_t)(t + 1) * HH];
        __syncthreads();                            // ONE barrier per step
        p ^= 1;
    }

    if (kh == 0) hn[((size_t)(n * BB + b)) * HH + o] = hlast;
}

// ---------------------------------------------------------------------------
extern "C" void kernel_launch(void* const* d_in, const int* in_sizes, int n_in,
                              void* d_out, int out_size, void* d_ws, size_t ws_size,
                              hipStream_t stream) {
    const float* x    = (const float*)d_in[0];
    const float* w_ih = (const float*)d_in[1];
    const float* w_hh = (const float*)d_in[2];
    const float* b_ih = (const float*)d_in[3];
    const float* b_hh = (const float*)d_in[4];

    float* out = (float*)d_out;                       // [N][B][T][H]
    float* hn  = out + (size_t)NN * BB * TT * HH;     // [N][B][H] tail

    hipFuncSetAttribute(reinterpret_cast<const void*>(k1_xproj),
                        hipFuncAttributeMaxDynamicSharedMemorySize, K1_LDS_BYTES);
    hipLaunchKernelGGL(k1_xproj, dim3(4, 64, 16), dim3(256), K1_LDS_BYTES, stream,
                       x, w_ih, b_ih, b_hh, out);

    hipFuncSetAttribute(reinterpret_cast<const void*>(k2_rnn),
                        hipFuncAttributeMaxDynamicSharedMemorySize, K2_LDS);
    hipLaunchKernelGGL(k2_rnn, dim3(NN * BB), dim3(1024), K2_LDS, stream,
                       w_hh, out, hn);
}